// Round 3
// baseline (263.456 us; speedup 1.0000x reference)
//
#include <hip/hip_runtime.h>

// Problem constants
#define V 32
#define CH 128
#define SP 4096   // 64*64

typedef __attribute__((ext_vector_type(8))) short bf16x8;
typedef __attribute__((ext_vector_type(4))) float f32x4;

__device__ __forceinline__ unsigned short bf16rne(float x) {
    union { float f; unsigned u; } v; v.f = x;
    unsigned r = v.u + 0x7fff + ((v.u >> 16) & 1);
    return (unsigned short)(r >> 16);
}

// XOR swizzle on the 8-elem k-block index; keeps staging b32 writes and
// fragment b128 reads <=2-way bank conflicts (free on gfx950, m136).
__device__ __forceinline__ int xswz(int s) { return (s & 7) ^ ((s >> 2) & 7); }

// row pointer into xsm for mixing index j at channel-residue r
__device__ __forceinline__ const float* xsm_row(const float* xsm, int j, int r) {
    return xsm + ((size_t)((j >> 2) * CH + (j & 3) * 32 + r)) * SP;
}

// ---------------------------------------------------------------------------
// prep_w: conv_w f32 [128][512] -> 4 bf16 slabs [sigma][o][c] stride 128
// ---------------------------------------------------------------------------
__global__ __launch_bounds__(128) void prep_w(const float* __restrict__ W,
                                              unsigned short* __restrict__ Wpad)
{
    int row = blockIdx.x;           // 0..511 = sigma*128 + o
    int j = threadIdx.x;
    int sigma = row >> 7, o = row & 127;
    Wpad[row * 128 + j] = bf16rne(W[o * 512 + sigma * 128 + j]);
}

// ---------------------------------------------------------------------------
// conv_full: fused K=512 1x1 conv over [x1 | up2(x2) | up4(x3) | up4(x4)]
// + bias -> xsm (d_out), plus gap[v][o] partial sums.
// Tile M=128 o x N=64 s (one h row).  A (W) fragments straight from global
// (L1/L2 resident); only the B (X) tile lives in LDS (16 KB).
// grid (64 sc, 32 v), block 256 = 4 waves.
// ---------------------------------------------------------------------------
__global__ __launch_bounds__(256) void conv_full(
    const float* __restrict__ x1, const float* __restrict__ x2,
    const float* __restrict__ x3, const float* __restrict__ x4,
    const unsigned short* __restrict__ Wpad, const float* __restrict__ bias,
    float* __restrict__ xsm, float* __restrict__ gap)
{
    __shared__ __align__(16) unsigned short Xl[64 * 128];
    __shared__ float gscr[4][64];
    const int v = blockIdx.y, sc = blockIdx.x, tid = threadIdx.x;
    const int lane = tid & 63, w = tid >> 6;
    const int l15 = lane & 15, quad = lane >> 4;
    const int o0 = (w >> 1) * 64, s0 = (w & 1) * 32;

    f32x4 acc[4][2];
#pragma unroll
    for (int it = 0; it < 4; ++it)
#pragma unroll
        for (int st = 0; st < 2; ++st) acc[it][st] = (f32x4){0.f, 0.f, 0.f, 0.f};

    // MFMA over the currently staged 128-channel chunk, W slab from global
    auto mfma_chunk = [&](const unsigned short* __restrict__ Wsl) {
#pragma unroll
        for (int ks = 0; ks < 4; ++ks) {
            int kb = ks * 4 + quad;
            bf16x8 af[4], bfr[2];
#pragma unroll
            for (int it = 0; it < 4; ++it)
                af[it] = *(const bf16x8*)&Wsl[(o0 + it * 16 + l15) * 128 + ks * 32 + quad * 8];
#pragma unroll
            for (int st = 0; st < 2; ++st) {
                int s = s0 + st * 16 + l15;
                bfr[st] = *(const bf16x8*)&Xl[s * 128 + ((kb ^ xswz(s)) * 8)];
            }
#pragma unroll
            for (int it = 0; it < 4; ++it)
#pragma unroll
                for (int st = 0; st < 2; ++st)
                    acc[it][st] = __builtin_amdgcn_mfma_f32_16x16x32_bf16(
                        af[it], bfr[st], acc[it][st], 0, 0, 0);
        }
    };

    // ---- sigma 0: x1 at full res ----
    {
        const int sq = tid & 15, cp0 = tid >> 4;
        const float* xbase = x1 + (size_t)v * CH * SP + sc * 64;
#pragma unroll
        for (int rep = 0; rep < 4; ++rep) {
            int c = (cp0 + rep * 16) * 2;
            const float* r0 = xbase + (size_t)c * SP + sq * 4;
            float4 va = *(const float4*)r0;
            float4 vb = *(const float4*)(r0 + SP);
            float a4[4] = {va.x, va.y, va.z, va.w};
            float b4[4] = {vb.x, vb.y, vb.z, vb.w};
#pragma unroll
            for (int i = 0; i < 4; ++i) {
                int s = sq * 4 + i;
                ushort2 pk; pk.x = bf16rne(a4[i]); pk.y = bf16rne(b4[i]);
                *(ushort2*)&Xl[s * 128 + (((c >> 3) ^ xswz(s)) * 8) + (c & 7)] = pk;
            }
        }
    }
    __syncthreads();
    mfma_chunk(Wpad);
    __syncthreads();

    // ---- sigma 1: up2(x2)  (h2 = sc>>1, s -> w2 = (s&63)>>1) ----
    {
        const int sqq = tid & 3, c = (tid >> 2) * 2;
        const float* b2 = x2 + (size_t)(v * CH + c) * 1024 + (sc >> 1) * 32 + sqq * 8;
        float4 a0 = *(const float4*)b2;
        float4 a1 = *(const float4*)(b2 + 4);
        float4 b0 = *(const float4*)(b2 + 1024);
        float4 b1 = *(const float4*)(b2 + 1028);
        float av[8] = {a0.x, a0.y, a0.z, a0.w, a1.x, a1.y, a1.z, a1.w};
        float bv[8] = {b0.x, b0.y, b0.z, b0.w, b1.x, b1.y, b1.z, b1.w};
#pragma unroll
        for (int i = 0; i < 8; ++i) {
            ushort2 pk; pk.x = bf16rne(av[i]); pk.y = bf16rne(bv[i]);
            int w2 = sqq * 8 + i;
#pragma unroll
            for (int d = 0; d < 2; ++d) {
                int s = w2 * 2 + d;
                *(ushort2*)&Xl[s * 128 + (((c >> 3) ^ xswz(s)) * 8) + (c & 7)] = pk;
            }
        }
    }
    __syncthreads();
    mfma_chunk(Wpad + 1 * 128 * 128);
    __syncthreads();

    // ---- sigma 2/3: up4(x3), up4(x4)  (h4 = sc>>2, w4 = (s&63)>>2) ----
#pragma unroll 1
    for (int ph = 0; ph < 2; ++ph) {
        const float* xp = ph ? x4 : x3;
        const int sqq = tid & 3, c = (tid >> 2) * 2;
        const float* b3 = xp + (size_t)(v * CH + c) * 256 + (sc >> 2) * 16 + sqq * 4;
        float4 a = *(const float4*)b3;
        float4 b = *(const float4*)(b3 + 256);
        float av[4] = {a.x, a.y, a.z, a.w};
        float bv[4] = {b.x, b.y, b.z, b.w};
#pragma unroll
        for (int i = 0; i < 4; ++i) {
            ushort2 pk; pk.x = bf16rne(av[i]); pk.y = bf16rne(bv[i]);
            int w4 = sqq * 4 + i;
#pragma unroll
            for (int d = 0; d < 4; ++d) {
                int s = w4 * 4 + d;
                *(ushort2*)&Xl[s * 128 + (((c >> 3) ^ xswz(s)) * 8) + (c & 7)] = pk;
            }
        }
        __syncthreads();
        mfma_chunk(Wpad + (2 + ph) * 128 * 128);
        __syncthreads();
    }

    // ---- epilogue: + bias, store xsm f32, gap sums ----
    float gs[16];
#pragma unroll
    for (int it = 0; it < 4; ++it)
#pragma unroll
        for (int reg = 0; reg < 4; ++reg) {
            int o = o0 + it * 16 + quad * 4 + reg;
            float b = bias[o];
            float* orow = xsm + ((size_t)(v * CH + o)) * SP + sc * 64;
            float lsum = 0.f;
#pragma unroll
            for (int st = 0; st < 2; ++st) {
                int s_l = s0 + st * 16 + l15;
                float val = acc[it][st][reg] + b;
                orow[s_l] = val;
                lsum += val;
            }
            gs[it * 4 + reg] = lsum;
        }
#pragma unroll
    for (int m = 1; m < 16; m <<= 1)
#pragma unroll
        for (int k = 0; k < 16; ++k) gs[k] += __shfl_xor(gs[k], m, 64);
    if (l15 == 0) {
#pragma unroll
        for (int it = 0; it < 4; ++it)
#pragma unroll
            for (int reg = 0; reg < 4; ++reg)
                gscr[w][it * 16 + quad * 4 + reg] = gs[it * 4 + reg];
    }
    __syncthreads();
    if (tid < 128) {
        int o = tid, b2i = (o >> 6) * 2;
        atomicAdd(&gap[v * CH + o], gscr[b2i][o & 63] + gscr[b2i + 1][o & 63]);
    }
}

// ---------------------------------------------------------------------------
// build_G: gap sums -> c_q -> att_C -> softmax*weight -> Gs = G - I (bf16,
// stride 128, [i][j]).  grid 128 (i) x 128 (j).
// ---------------------------------------------------------------------------
__global__ __launch_bounds__(128) void build_G(
    const float* __restrict__ gap, const float* __restrict__ gammap,
    const float* __restrict__ weight, unsigned short* __restrict__ GsPad)
{
    __shared__ float cq[32][128];
    __shared__ float red[128];
    const int i = blockIdx.x, j = threadIdx.x;
    const float g = gammap[0];

    float gb = 0.f;
    for (int v = 0; v < 32; ++v) gb += gap[v * CH + j];
    gb = gb * (1.f / 32.f) * (1.f / 4096.f) * g;
    for (int v = 0; v < 32; ++v) cq[v][j] = gap[v * CH + j] * (1.f / 4096.f) + gb;
    __syncthreads();

    float a = 0.f;
    for (int v = 0; v < 32; ++v) a += cq[v][i] * cq[v][j];

    red[j] = a; __syncthreads();
    float m = -1e30f;
    for (int t = 0; t < 128; ++t) m = fmaxf(m, red[t]);
    __syncthreads();
    float e = __expf(a - m);
    red[j] = e; __syncthreads();
    float ssum = 0.f;
    for (int t = 0; t < 128; ++t) ssum += red[t];
    float cm = e / ssum * weight[j] + ((i == j) ? 1.f : 0.f);   // (C_mat + I)[i][j]
    __syncthreads();
    red[j] = cm; __syncthreads();
    float rs = 0.f;
    for (int t = (j & 3); t < 128; t += 4) rs += red[t];
    float gfull = cm + g * (1.f / 32.f) * rs;
    GsPad[i * 128 + j] = bf16rne(gfull - ((i == j) ? 1.f : 0.f));  // minus identity
}

// ---------------------------------------------------------------------------
// apply_G: out[i][s] = sum_j Gs[i][j]*Xt[j][s] + xsm[i][s] (f32 residual).
// Gs fragments straight from global; only X tile in LDS.  In-place on xsm:
// block read-set == write-set, staged to LDS before any store.
// grid (64 sc, 32 r), block 256.
// ---------------------------------------------------------------------------
__global__ __launch_bounds__(256) void apply_G(
    float* __restrict__ xsm, const unsigned short* __restrict__ GsPad)
{
    __shared__ __align__(16) unsigned short Xl[64 * 128];
    const int r = blockIdx.y, sc = blockIdx.x, tid = threadIdx.x;
    const int lane = tid & 63, w = tid >> 6;
    const int l15 = lane & 15, quad = lane >> 4;
    const int i0 = (w >> 1) * 64, s0 = (w & 1) * 32;
    const int sq = tid & 15, cp0 = tid >> 4;

    f32x4 acc[4][2];
#pragma unroll
    for (int it = 0; it < 4; ++it)
#pragma unroll
        for (int st = 0; st < 2; ++st) acc[it][st] = (f32x4){0.f, 0.f, 0.f, 0.f};

    // stage Xt[j][s] -> Xl[s][j] bf16 (swizzled); j rows gathered from xsm
#pragma unroll
    for (int rep = 0; rep < 4; ++rep) {
        int c = (cp0 + rep * 16) * 2;     // j pair
        const float* r0 = xsm_row(xsm, c, r) + sc * 64 + sq * 4;
        const float* r1 = xsm_row(xsm, c + 1, r) + sc * 64 + sq * 4;
        float4 va = *(const float4*)r0;
        float4 vb = *(const float4*)r1;
        float a4[4] = {va.x, va.y, va.z, va.w};
        float b4[4] = {vb.x, vb.y, vb.z, vb.w};
#pragma unroll
        for (int i = 0; i < 4; ++i) {
            int s = sq * 4 + i;
            ushort2 pk; pk.x = bf16rne(a4[i]); pk.y = bf16rne(b4[i]);
            *(ushort2*)&Xl[s * 128 + (((c >> 3) ^ xswz(s)) * 8) + (c & 7)] = pk;
        }
    }
    __syncthreads();
#pragma unroll
    for (int ks = 0; ks < 4; ++ks) {
        int kb = ks * 4 + quad;
        bf16x8 af[4], bfr[2];
#pragma unroll
        for (int it = 0; it < 4; ++it)
            af[it] = *(const bf16x8*)&GsPad[(i0 + it * 16 + l15) * 128 + ks * 32 + quad * 8];
#pragma unroll
        for (int st = 0; st < 2; ++st) {
            int s = s0 + st * 16 + l15;
            bfr[st] = *(const bf16x8*)&Xl[s * 128 + ((kb ^ xswz(s)) * 8)];
        }
#pragma unroll
        for (int it = 0; it < 4; ++it)
#pragma unroll
            for (int st = 0; st < 2; ++st)
                acc[it][st] = __builtin_amdgcn_mfma_f32_16x16x32_bf16(
                    af[it], bfr[st], acc[it][st], 0, 0, 0);
    }
    // epilogue: f32 residual (own write address) + store
#pragma unroll
    for (int it = 0; it < 4; ++it)
#pragma unroll
        for (int reg = 0; reg < 4; ++reg) {
            int i = i0 + it * 16 + quad * 4 + reg;
            float* rowp = (float*)xsm_row(xsm, i, r) + sc * 64;
#pragma unroll
            for (int st = 0; st < 2; ++st) {
                int s_l = s0 + st * 16 + l15;
                rowp[s_l] = rowp[s_l] + acc[it][st][reg];
            }
        }
}

// ---------------------------------------------------------------------------
extern "C" void kernel_launch(void* const* d_in, const int* in_sizes, int n_in,
                              void* d_out, int out_size, void* d_ws, size_t ws_size,
                              hipStream_t stream)
{
    const float* x1     = (const float*)d_in[0];
    const float* x2     = (const float*)d_in[1];
    const float* x3     = (const float*)d_in[2];
    const float* x4     = (const float*)d_in[3];
    const float* conv_w = (const float*)d_in[4];
    const float* conv_b = (const float*)d_in[5];
    const float* gamma  = (const float*)d_in[6];
    const float* weight = (const float*)d_in[7];
    // d_in[8] = lin_w: mathematically unused (row-constant softmax -> uniform)

    float* out = (float*)d_out;     // doubles as x_sm (in-place pass 2)
    float* ws  = (float*)d_ws;

    // ws layout: gap f32[4096] | Wpad bf16[4*128*128] | GsPad bf16[128*128]
    float* gap = ws;
    unsigned short* Wpad  = (unsigned short*)(ws + 4096);
    unsigned short* GsPad = Wpad + 4 * 128 * 128;

    hipMemsetAsync(gap, 0, 4096 * sizeof(float), stream);

    prep_w<<<512, 128, 0, stream>>>(conv_w, Wpad);
    conv_full<<<dim3(64, 32), 256, 0, stream>>>(x1, x2, x3, x4, Wpad, conv_b, out, gap);
    build_G<<<128, 128, 0, stream>>>(gap, gamma, weight, GsPad);
    apply_G<<<dim3(64, 32), 256, 0, stream>>>(out, GsPad);
}

// Round 4
// 234.410 us; speedup vs baseline: 1.1239x; 1.1239x over previous
//
#include <hip/hip_runtime.h>

// Problem constants
#define V 32
#define CH 128
#define SP 4096   // 64*64

typedef __attribute__((ext_vector_type(8))) short bf16x8;
typedef __attribute__((ext_vector_type(4))) float f32x4;

__device__ __forceinline__ unsigned short bf16rne(float x) {
    union { float f; unsigned u; } v; v.f = x;
    unsigned r = v.u + 0x7fff + ((v.u >> 16) & 1);
    return (unsigned short)(r >> 16);
}

// XOR swizzle: 8-short (16B) column-block index mixed with row index.
// Gives <=2-way conflicts for both staging writes and b128 fragment reads.
__device__ __forceinline__ int swz(int row) { return (row & 7) ^ ((row >> 2) & 7); }

// row pointer into xsm for mixing index j at channel-residue r
__device__ __forceinline__ float* xsm_row(float* xsm, int j, int r) {
    return xsm + ((size_t)((j >> 2) * CH + (j & 3) * 32 + r)) * SP;
}

// ---------------------------------------------------------------------------
// prep_w: conv_w f32 [128 o][512 c] -> 8 pre-swizzled bf16 LDS images
// (chunk = sigma*2+khalf, 64 c each): Wimg[chunk][o*64 + ((cl>>3)^swz(o))*8 + (cl&7)]
// ---------------------------------------------------------------------------
__global__ __launch_bounds__(128) void prep_w(const float* __restrict__ W,
                                              unsigned short* __restrict__ Wimg)
{
    int row = blockIdx.x;            // sigma*128 + o
    int j = threadIdx.x;             // 0..127 source col within sigma
    int sigma = row >> 7, o = row & 127;
    int khalf = j >> 6, cl = j & 63;
    int chunk = sigma * 2 + khalf;
    int col = (((cl >> 3) ^ swz(o)) * 8) + (cl & 7);
    Wimg[chunk * 8192 + o * 64 + col] = bf16rne(W[o * 512 + sigma * 128 + j]);
}

// ---------------------------------------------------------------------------
// conv_full: fused K=512 1x1 conv over [x1 | up2(x2) | up4(x3) | up4(x4)]
// + bias -> xsm (d_out), plus gap[v][o] sums.  Tile M=128 o x N=128 s
// (2 h rows), BK=64 chunks, W chunk + X tile in LDS (33 KB).
// grid (32 sc, 32 v), block 256 = 4 waves (2x2 wave grid, 64x64/wave).
// ---------------------------------------------------------------------------
__global__ __launch_bounds__(256, 4) void conv_full(
    const float* __restrict__ x1, const float* __restrict__ x2,
    const float* __restrict__ x3, const float* __restrict__ x4,
    const unsigned short* __restrict__ Wimg, const float* __restrict__ bias,
    float* __restrict__ xsm, float* __restrict__ gap)
{
    __shared__ __align__(16) unsigned short Wl[128 * 64];
    __shared__ __align__(16) unsigned short Xl[128 * 64];
    __shared__ float gscr[4][64];
    const int v = blockIdx.y, sc = blockIdx.x, tid = threadIdx.x;
    const int lane = tid & 63, wv = tid >> 6;
    const int l15 = lane & 15, quad = lane >> 4;
    const int o0 = (wv >> 1) * 64, s0l = (wv & 1) * 64;

    f32x4 acc[4][4];
#pragma unroll
    for (int it = 0; it < 4; ++it)
#pragma unroll
        for (int st = 0; st < 4; ++st) acc[it][st] = (f32x4){0.f, 0.f, 0.f, 0.f};

#pragma unroll 1
    for (int chunk = 0; chunk < 8; ++chunk) {
        const int sigma = chunk >> 1, khalf = chunk & 1;
        __syncthreads();
        // --- stage W chunk: straight 16 KB copy of pre-swizzled image ---
        {
            const float4* wsrc = (const float4*)(Wimg + chunk * 8192);
            float4* wdst = (float4*)Wl;
#pragma unroll
            for (int p = 0; p < 4; ++p) wdst[tid + p * 256] = wsrc[tid + p * 256];
        }
        // --- stage X tile [128 s][64 c] bf16 swizzled, with fused upsample ---
        if (sigma == 0) {
            int cp = tid >> 3, sq8 = tid & 7;
            int c = cp * 2;
            const float* xb = x1 + ((size_t)(v * CH + khalf * 64 + c)) * SP + sc * 128;
#pragma unroll
            for (int rep = 0; rep < 4; ++rep) {
                int sq = sq8 + rep * 8;
                float4 va = *(const float4*)(xb + sq * 4);
                float4 vb = *(const float4*)(xb + SP + sq * 4);
                float a4[4] = {va.x, va.y, va.z, va.w};
                float b4[4] = {vb.x, vb.y, vb.z, vb.w};
#pragma unroll
                for (int i = 0; i < 4; ++i) {
                    int s = sq * 4 + i;
                    ushort2 pk; pk.x = bf16rne(a4[i]); pk.y = bf16rne(b4[i]);
                    *(ushort2*)&Xl[s * 64 + (((c >> 3) ^ swz(s)) * 8) + (c & 7)] = pk;
                }
            }
        } else if (sigma == 1) {
            // up2: tile h = {2sc, 2sc+1} -> h2 = sc; w2 = 0..31
            int cp = tid >> 3, wg = tid & 7;
            int c = cp * 2;
            const float* xb = x2 + ((size_t)(v * CH + khalf * 64 + c)) * 1024 + sc * 32 + wg * 4;
            float4 va = *(const float4*)xb;
            float4 vb = *(const float4*)(xb + 1024);
            float a4[4] = {va.x, va.y, va.z, va.w};
            float b4[4] = {vb.x, vb.y, vb.z, vb.w};
#pragma unroll
            for (int k = 0; k < 4; ++k) {
                int w2 = wg * 4 + k;
                ushort2 pk; pk.x = bf16rne(a4[k]); pk.y = bf16rne(b4[k]);
#pragma unroll
                for (int dh = 0; dh < 2; ++dh)
#pragma unroll
                    for (int dw = 0; dw < 2; ++dw) {
                        int s = dh * 64 + w2 * 2 + dw;
                        *(ushort2*)&Xl[s * 64 + (((c >> 3) ^ swz(s)) * 8) + (c & 7)] = pk;
                    }
            }
        } else {
            // up4: h4 = sc>>1 (both tile h rows); w4 = 0..15
            const float* xp = (sigma == 2) ? x3 : x4;
            int cp = tid >> 3, sel = (tid >> 1) & 3, dh = tid & 1;
            int c = cp * 2;
            const float* xb = xp + ((size_t)(v * CH + khalf * 64 + c)) * 256 + (sc >> 1) * 16 + sel * 4;
            float4 va = *(const float4*)xb;
            float4 vb = *(const float4*)(xb + 256);
            float a4[4] = {va.x, va.y, va.z, va.w};
            float b4[4] = {vb.x, vb.y, vb.z, vb.w};
#pragma unroll
            for (int k = 0; k < 4; ++k) {
                int w4 = sel * 4 + k;
                ushort2 pk; pk.x = bf16rne(a4[k]); pk.y = bf16rne(b4[k]);
#pragma unroll
                for (int dw = 0; dw < 4; ++dw) {
                    int s = dh * 64 + w4 * 4 + dw;
                    *(ushort2*)&Xl[s * 64 + (((c >> 3) ^ swz(s)) * 8) + (c & 7)] = pk;
                }
            }
        }
        __syncthreads();
        // --- MFMA: 2 k-steps x 4x4 tiles ---
#pragma unroll
        for (int ks = 0; ks < 2; ++ks) {
            int kb = ks * 4 + quad;      // 16B block index 0..7
            bf16x8 af[4], bfr[4];
#pragma unroll
            for (int it = 0; it < 4; ++it) {
                int o = o0 + it * 16 + l15;
                af[it] = *(const bf16x8*)&Wl[o * 64 + ((kb ^ swz(o)) * 8)];
            }
#pragma unroll
            for (int st = 0; st < 4; ++st) {
                int s = s0l + st * 16 + l15;
                bfr[st] = *(const bf16x8*)&Xl[s * 64 + ((kb ^ swz(s)) * 8)];
            }
#pragma unroll
            for (int it = 0; it < 4; ++it)
#pragma unroll
                for (int st = 0; st < 4; ++st)
                    acc[it][st] = __builtin_amdgcn_mfma_f32_16x16x32_bf16(
                        af[it], bfr[st], acc[it][st], 0, 0, 0);
        }
    }

    // ---- epilogue: + bias, store xsm f32, gap sums ----
    float gs[16];
#pragma unroll
    for (int it = 0; it < 4; ++it)
#pragma unroll
        for (int reg = 0; reg < 4; ++reg) {
            int o = o0 + it * 16 + quad * 4 + reg;
            float b = bias[o];
            float* orow = xsm + ((size_t)(v * CH + o)) * SP + sc * 128;
            float lsum = 0.f;
#pragma unroll
            for (int st = 0; st < 4; ++st) {
                int sl = s0l + st * 16 + l15;
                float val = acc[it][st][reg] + b;
                orow[sl] = val;
                lsum += val;
            }
            gs[it * 4 + reg] = lsum;
        }
#pragma unroll
    for (int m = 1; m < 16; m <<= 1)
#pragma unroll
        for (int k = 0; k < 16; ++k) gs[k] += __shfl_xor(gs[k], m, 64);
    if (l15 == 0) {
#pragma unroll
        for (int it = 0; it < 4; ++it)
#pragma unroll
            for (int reg = 0; reg < 4; ++reg)
                gscr[wv][it * 16 + quad * 4 + reg] = gs[it * 4 + reg];
    }
    __syncthreads();
    if (tid < 128) {
        int o = tid, b2 = (o >> 6) * 2;
        atomicAdd(&gap[v * CH + o], gscr[b2][o & 63] + gscr[b2 + 1][o & 63]);
    }
}

// ---------------------------------------------------------------------------
// build_G: gap sums -> c_q -> att_C -> softmax*weight -> Gs = G - I, stored
// as pre-swizzled bf16 LDS image: Gimg[i*128 + ((jb&8)|((jb&7)^swz(i)))*8 + (j&7)]
// ---------------------------------------------------------------------------
__global__ __launch_bounds__(128) void build_G(
    const float* __restrict__ gap, const float* __restrict__ gammap,
    const float* __restrict__ weight, unsigned short* __restrict__ Gimg)
{
    __shared__ float cq[32][128];
    __shared__ float red[128];
    const int i = blockIdx.x, j = threadIdx.x;
    const float g = gammap[0];

    float gb = 0.f;
    for (int v = 0; v < 32; ++v) gb += gap[v * CH + j];
    gb = gb * (1.f / 32.f) * (1.f / 4096.f) * g;
    for (int v = 0; v < 32; ++v) cq[v][j] = gap[v * CH + j] * (1.f / 4096.f) + gb;
    __syncthreads();

    float a = 0.f;
    for (int v = 0; v < 32; ++v) a += cq[v][i] * cq[v][j];

    red[j] = a; __syncthreads();
    float m = -1e30f;
    for (int t = 0; t < 128; ++t) m = fmaxf(m, red[t]);
    __syncthreads();
    float e = __expf(a - m);
    red[j] = e; __syncthreads();
    float ssum = 0.f;
    for (int t = 0; t < 128; ++t) ssum += red[t];
    float cm = e / ssum * weight[j] + ((i == j) ? 1.f : 0.f);   // (C_mat + I)[i][j]
    __syncthreads();
    red[j] = cm; __syncthreads();
    float rs = 0.f;
    for (int t = (j & 3); t < 128; t += 4) rs += red[t];
    float gfull = cm + g * (1.f / 32.f) * rs;
    float gsv = gfull - ((i == j) ? 1.f : 0.f);                  // minus identity
    int jb = j >> 3;
    int blk = (jb & 8) | ((jb & 7) ^ swz(i));
    Gimg[i * 128 + blk * 8 + (j & 7)] = bf16rne(gsv);
}

// ---------------------------------------------------------------------------
// apply_G: out[i][s] = sum_j Gs[i][j]*X[j][s] + xsm[i][s] (f32 residual).
// Gs (32 KB) resident in LDS; X staged in 2 j-chunks of 64 (16 KB).
// In-place on xsm: block read-set == write-set, all reads precede stores.
// Tile M=128 i x N=128 s.  grid (32 sc, 32 r), block 256.
// ---------------------------------------------------------------------------
__global__ __launch_bounds__(256, 3) void apply_G(
    float* __restrict__ xsm, const unsigned short* __restrict__ Gimg)
{
    __shared__ __align__(16) unsigned short Gl[128 * 128];
    __shared__ __align__(16) unsigned short Xl[128 * 64];
    const int r = blockIdx.y, sc = blockIdx.x, tid = threadIdx.x;
    const int lane = tid & 63, wv = tid >> 6;
    const int l15 = lane & 15, quad = lane >> 4;
    const int i0 = (wv >> 1) * 64, s0l = (wv & 1) * 64;

    // stage Gs image (32 KB straight copy)
    {
        const float4* gsrc = (const float4*)Gimg;
        float4* gdst = (float4*)Gl;
#pragma unroll
        for (int p = 0; p < 8; ++p) gdst[tid + p * 256] = gsrc[tid + p * 256];
    }

    f32x4 acc[4][4];
#pragma unroll
    for (int it = 0; it < 4; ++it)
#pragma unroll
        for (int st = 0; st < 4; ++st) acc[it][st] = (f32x4){0.f, 0.f, 0.f, 0.f};

#pragma unroll 1
    for (int jc = 0; jc < 2; ++jc) {
        __syncthreads();
        // stage X chunk [128 s][64 j] bf16 swizzled
        {
            int cp = tid >> 3, sq8 = tid & 7;
            int c = cp * 2;
            const float* ra = xsm_row(xsm, jc * 64 + c, r) + sc * 128;
            const float* rb = xsm_row(xsm, jc * 64 + c + 1, r) + sc * 128;
#pragma unroll
            for (int rep = 0; rep < 4; ++rep) {
                int sq = sq8 + rep * 8;
                float4 va = *(const float4*)(ra + sq * 4);
                float4 vb = *(const float4*)(rb + sq * 4);
                float a4[4] = {va.x, va.y, va.z, va.w};
                float b4[4] = {vb.x, vb.y, vb.z, vb.w};
#pragma unroll
                for (int i = 0; i < 4; ++i) {
                    int s = sq * 4 + i;
                    ushort2 pk; pk.x = bf16rne(a4[i]); pk.y = bf16rne(b4[i]);
                    *(ushort2*)&Xl[s * 64 + (((c >> 3) ^ swz(s)) * 8) + (c & 7)] = pk;
                }
            }
        }
        __syncthreads();
#pragma unroll
        for (int ks = 0; ks < 2; ++ks) {
            int kbl = ks * 4 + quad;       // Xl block 0..7
            int kgl = jc * 8 + kbl;        // Gl block 0..15
            bf16x8 af[4], bfr[4];
#pragma unroll
            for (int it = 0; it < 4; ++it) {
                int i = i0 + it * 16 + l15;
                int blk = (kgl & 8) | ((kgl & 7) ^ swz(i));
                af[it] = *(const bf16x8*)&Gl[i * 128 + blk * 8];
            }
#pragma unroll
            for (int st = 0; st < 4; ++st) {
                int s = s0l + st * 16 + l15;
                bfr[st] = *(const bf16x8*)&Xl[s * 64 + ((kbl ^ swz(s)) * 8)];
            }
#pragma unroll
            for (int it = 0; it < 4; ++it)
#pragma unroll
                for (int st = 0; st < 4; ++st)
                    acc[it][st] = __builtin_amdgcn_mfma_f32_16x16x32_bf16(
                        af[it], bfr[st], acc[it][st], 0, 0, 0);
        }
    }
    // epilogue: f32 residual (each lane reads exactly its own store address)
#pragma unroll
    for (int it = 0; it < 4; ++it)
#pragma unroll
        for (int reg = 0; reg < 4; ++reg) {
            int i = i0 + it * 16 + quad * 4 + reg;
            float* rowp = xsm_row(xsm, i, r) + sc * 128;
#pragma unroll
            for (int st = 0; st < 4; ++st) {
                int sl = s0l + st * 16 + l15;
                rowp[sl] = rowp[sl] + acc[it][st][reg];
            }
        }
}

// ---------------------------------------------------------------------------
extern "C" void kernel_launch(void* const* d_in, const int* in_sizes, int n_in,
                              void* d_out, int out_size, void* d_ws, size_t ws_size,
                              hipStream_t stream)
{
    const float* x1     = (const float*)d_in[0];
    const float* x2     = (const float*)d_in[1];
    const float* x3     = (const float*)d_in[2];
    const float* x4     = (const float*)d_in[3];
    const float* conv_w = (const float*)d_in[4];
    const float* conv_b = (const float*)d_in[5];
    const float* gamma  = (const float*)d_in[6];
    const float* weight = (const float*)d_in[7];
    // d_in[8] = lin_w: mathematically unused (row-constant softmax -> uniform)

    float* out = (float*)d_out;     // doubles as x_sm (in-place pass 2)
    float* ws  = (float*)d_ws;

    // ws layout: gap f32[4096] | Wimg bf16[8*8192] | Gimg bf16[128*128]
    float* gap = ws;
    unsigned short* Wimg = (unsigned short*)(ws + 4096);
    unsigned short* Gimg = Wimg + 8 * 8192;

    hipMemsetAsync(gap, 0, 4096 * sizeof(float), stream);

    prep_w<<<512, 128, 0, stream>>>(conv_w, Wimg);
    conv_full<<<dim3(32, 32), 256, 0, stream>>>(x1, x2, x3, x4, Wimg, conv_b, out, gap);
    build_G<<<128, 128, 0, stream>>>(gap, gamma, weight, Gimg);
    apply_G<<<dim3(32, 32), 256, 0, stream>>>(out, Gimg);
}